// Round 6
// baseline (378.000 us; speedup 1.0000x reference)
//
#include <hip/hip_runtime.h>
#include <math.h>

// Static problem shape (from reference setup_inputs)
#define BB    256                // graphs
#define NPER  512                // nodes per graph
#define DD    256                // feature dim
#define KK    256                // kept nodes per graph
#define EPG   (NPER * 16)        // 8192 edges per graph
#define NN    (BB * NPER)
#define EE    (BB * EPG)

// native clang vector type — required by __builtin_nontemporal_store
typedef float vf4 __attribute__((ext_vector_type(4)));

// ---------------- k_dot: hraw[v] = dot(x[v], W) ----------------
// wave per 4 rows (ILP), 256-thread blocks -> 16 rows/block, 8192 blocks.
__global__ __launch_bounds__(256) void k_dot(const float* __restrict__ x,
                                             const float* __restrict__ W,
                                             float* __restrict__ hraw) {
    const int wave = threadIdx.x >> 6;
    const int lane = threadIdx.x & 63;
    const int r0   = blockIdx.x * 16 + wave * 4;
    const float4 wv = ((const float4*)W)[lane];
    const float4* p = (const float4*)(x + ((size_t)r0 << 8));
    float4 a0 = p[lane];
    float4 a1 = p[64 + lane];
    float4 a2 = p[128 + lane];
    float4 a3 = p[192 + lane];
    float d0 = a0.x * wv.x + a0.y * wv.y + a0.z * wv.z + a0.w * wv.w;
    float d1 = a1.x * wv.x + a1.y * wv.y + a1.z * wv.z + a1.w * wv.w;
    float d2 = a2.x * wv.x + a2.y * wv.y + a2.z * wv.z + a2.w * wv.w;
    float d3 = a3.x * wv.x + a3.y * wv.y + a3.z * wv.z + a3.w * wv.w;
    #pragma unroll
    for (int off = 32; off > 0; off >>= 1) {
        d0 += __shfl_down(d0, off, 64);
        d1 += __shfl_down(d1, off, 64);
        d2 += __shfl_down(d2, off, 64);
        d3 += __shfl_down(d3, off, 64);
    }
    if (lane == 0) {
        hraw[r0]     = d0;
        hraw[r0 + 1] = d1;
        hraw[r0 + 2] = d2;
        hraw[r0 + 3] = d3;
    }
}

// ---------------- k_graph: per-graph small-data pipeline, 1024 threads ------
__global__ __launch_bounds__(1024) void k_graph(
        const float* __restrict__ hraw, const float* __restrict__ b,
        const int* __restrict__ src, const int* __restrict__ dst,
        float* __restrict__ out_perm, float* __restrict__ tsvg,
        float* __restrict__ emask, float* __restrict__ nnn) {
    __shared__ unsigned int es2[EPG / 2];       // 16 KB packed src id pairs
    __shared__ unsigned int ed2[EPG / 2];       // 16 KB packed dst id pairs
    __shared__ int   degs[NPER];
    __shared__ int   degd[NPER];
    __shared__ float hl[NPER];
    __shared__ float aggl[NPER];
    __shared__ float scl[NPER];
    __shared__ unsigned long long keys[NPER];   // LDS stages of the sort
    __shared__ float keepf[NPER];               // 1.0 if kept else 0.0

    const int g = blockIdx.x;
    const int t = threadIdx.x;                  // 0..1023
    const int nbase = g << 9;

    // issue all global loads up front (edges + this thread's hraw)
    const int4* s4 = (const int4*)(src + (size_t)g * EPG);
    const int4* d4 = (const int4*)(dst + (size_t)g * EPG);
    int4 sva = s4[t], dva = d4[t];
    int4 svb = s4[t + 1024], dvb = d4[t + 1024];
    float hv = (t < NPER) ? hraw[nbase + t] : 0.0f;

    if (t < NPER) { degs[t] = 0; degd[t] = 0; aggl[t] = 0.0f; keepf[t] = 0.0f; }
    __syncthreads();

    // ---- pack edges to LDS + degree histograms ----
    {
        unsigned int a0 = (unsigned int)(sva.x - nbase), a1 = (unsigned int)(sva.y - nbase);
        unsigned int a2 = (unsigned int)(sva.z - nbase), a3 = (unsigned int)(sva.w - nbase);
        es2[t * 2]     = a0 | (a1 << 16);
        es2[t * 2 + 1] = a2 | (a3 << 16);
        atomicAdd(&degs[a0], 1); atomicAdd(&degs[a1], 1);
        atomicAdd(&degs[a2], 1); atomicAdd(&degs[a3], 1);
        unsigned int c0 = (unsigned int)(dva.x - nbase), c1 = (unsigned int)(dva.y - nbase);
        unsigned int c2 = (unsigned int)(dva.z - nbase), c3 = (unsigned int)(dva.w - nbase);
        ed2[t * 2]     = c0 | (c1 << 16);
        ed2[t * 2 + 1] = c2 | (c3 << 16);
        atomicAdd(&degd[c0], 1); atomicAdd(&degd[c1], 1);
        atomicAdd(&degd[c2], 1); atomicAdd(&degd[c3], 1);
    }
    {
        int i = t + 1024;
        unsigned int a0 = (unsigned int)(svb.x - nbase), a1 = (unsigned int)(svb.y - nbase);
        unsigned int a2 = (unsigned int)(svb.z - nbase), a3 = (unsigned int)(svb.w - nbase);
        es2[i * 2]     = a0 | (a1 << 16);
        es2[i * 2 + 1] = a2 | (a3 << 16);
        atomicAdd(&degs[a0], 1); atomicAdd(&degs[a1], 1);
        atomicAdd(&degs[a2], 1); atomicAdd(&degs[a3], 1);
        unsigned int c0 = (unsigned int)(dvb.x - nbase), c1 = (unsigned int)(dvb.y - nbase);
        unsigned int c2 = (unsigned int)(dvb.z - nbase), c3 = (unsigned int)(dvb.w - nbase);
        ed2[i * 2]     = c0 | (c1 << 16);
        ed2[i * 2 + 1] = c2 | (c3 << 16);
        atomicAdd(&degd[c0], 1); atomicAdd(&degd[c1], 1);
        atomicAdd(&degd[c2], 1); atomicAdd(&degd[c3], 1);
    }
    __syncthreads();

    // ---- h = hraw * rsqrt(max(deg_out,1)) ----
    if (t < NPER) hl[t] = hv * rsqrtf(fmaxf((float)degs[t], 1.0f));
    __syncthreads();

    // ---- agg[dst] += h[src]  (4 packed pairs per thread) ----
    #pragma unroll
    for (int i = t; i < EPG / 2; i += 1024) {
        unsigned int sp = es2[i], dp = ed2[i];
        atomicAdd(&aggl[dp & 0xFFFFu], hl[sp & 0xFFFFu]);
        atomicAdd(&aggl[dp >> 16],     hl[sp >> 16]);
    }
    __syncthreads();

    // ---- score + sort key (monotone float->uint; idx asc on ties) ----
    unsigned long long key = 0;
    if (t < NPER) {
        float sc = aggl[t] * rsqrtf(fmaxf((float)degd[t], 1.0f)) + b[0];
        scl[t] = sc;
        unsigned int u = __float_as_uint(sc);
        u = (u & 0x80000000u) ? ~u : (u | 0x80000000u);
        key = ((unsigned long long)u << 32) |
              (unsigned long long)(0xFFFFFFFFu - (unsigned)t);
    }
    __syncthreads();

    // ---- hybrid bitonic sort, 512 keys, descending, stable ----
    for (int kk = 2; kk <= NPER; kk <<= 1) {
        for (int j = kk >> 1; j > 0; j >>= 1) {
            if (j >= 64) {
                __syncthreads();                    // WAR: prior reads done
                if (t < NPER) keys[t] = key;
                __syncthreads();
                if (t < NPER) {
                    unsigned long long c = keys[t ^ j];
                    bool lower = ((t & j) == 0);
                    bool up    = ((t & kk) == 0);
                    bool takeMax = (up == lower);
                    key = takeMax ? (key >= c ? key : c)
                                  : (key >= c ? c : key);
                }
            } else {
                if (t < NPER) {
                    unsigned long long c = __shfl_xor(key, j, 64);
                    bool lower = ((t & j) == 0);
                    bool up    = ((t & kk) == 0);
                    bool takeMax = (up == lower);
                    key = takeMax ? (key >= c ? key : c)
                                  : (key >= c ? c : key);
                }
            }
        }
    }

    // ---- top-256: perm, keep flags, tanh(score) to global ----
    if (t < KK) {
        int idx = (int)(0xFFFFFFFFu - (unsigned int)(key & 0xFFFFFFFFull));
        out_perm[(g << 8) + t] = (float)(nbase + idx);
        tsvg[(g << 8) + t] = tanhf(scl[idx]);
        keepf[idx] = 1.0f;
    }
    __syncthreads();

    // ---- edge mask (packed LDS reads, non-temporal float4 stores) ----
    vf4* em4 = (vf4*)(emask + ((size_t)g << 13));
    #pragma unroll
    for (int i = t; i < EPG / 4; i += 1024) {
        unsigned int sp0 = es2[i * 2], sp1 = es2[i * 2 + 1];
        unsigned int dp0 = ed2[i * 2], dp1 = ed2[i * 2 + 1];
        vf4 m;
        m.x = keepf[sp0 & 0xFFFFu] * keepf[dp0 & 0xFFFFu];
        m.y = keepf[sp0 >> 16]     * keepf[dp0 >> 16];
        m.z = keepf[sp1 & 0xFFFFu] * keepf[dp1 & 0xFFFFu];
        m.w = keepf[sp1 >> 16]     * keepf[dp1 >> 16];
        __builtin_nontemporal_store(m, &em4[i]);
    }
    if (g == 0 && t < BB) nnn[t] = (float)KK;
}

// ---------------- k_feat: feat[r] = x[perm[r]] * tsv[r] ---------------------
__global__ __launch_bounds__(256) void k_feat(
        const float* __restrict__ x,
        const float* __restrict__ operm, const float* __restrict__ tsvg,
        float* __restrict__ feat) {
    __shared__ int   rsel[8];
    __shared__ float rts[8];
    const int blk = blockIdx.x;                 // 0..8191
    const int g   = blk >> 5;                   // 32 blocks per graph
    const int r0  = (blk & 31) << 3;            // first of 8 ranks
    const int t = threadIdx.x;
    const int wave = t >> 6;
    const int lane = t & 63;
    if (t < 8) {
        const int gr = (g << 8) + r0 + t;
        rsel[t] = (int)operm[gr];               // global node id (exact in f32)
        rts[t]  = tsvg[gr];
    }
    __syncthreads();
    #pragma unroll
    for (int u = 0; u < 2; ++u) {
        const int j = (wave << 1) + u;          // 0..7
        const int row = rsel[j];
        const float s = rts[j];
        float4 v = ((const float4*)(x + ((size_t)row << 8)))[lane];
        vf4 o = { v.x * s, v.y * s, v.z * s, v.w * s };
        __builtin_nontemporal_store(
            o, (vf4*)(feat + ((size_t)((g << 8) + r0 + j) << 8)) + lane);
    }
}

extern "C" void kernel_launch(void* const* d_in, const int* in_sizes, int n_in,
                              void* d_out, int out_size, void* d_ws, size_t ws_size,
                              hipStream_t stream) {
    const float* x   = (const float*)d_in[0];
    const float* W   = (const float*)d_in[1];
    const float* b   = (const float*)d_in[2];
    const int*   src = (const int*)d_in[3];
    const int*   dst = (const int*)d_in[4];
    // d_in[5] = num_nodes (uniform 512, unused)

    float* out   = (float*)d_out;
    float* feat  = out;                                   // [B*k, D]
    float* operm = feat + (size_t)BB * KK * DD;           // [B*k]
    float* emask = operm + (size_t)BB * KK;               // [E]
    float* nnn   = emask + (size_t)EE;                    // [B]

    float* hraw = (float*)d_ws;                           // [N]
    float* tsvg = hraw + NN;                              // [B*k]

    // ---- TIMING PROBE (this round): asymmetric shadow multiplicities ----
    // dur - 256.0  =  2*(T_dot+gap) + 4*(T_feat+gap)   ->  solves both
    float* sh_hraw = tsvg + (size_t)BB * KK;              // [N] scratch
    float* sh_feat = sh_hraw + NN;                        // [B*k*D] scratch (64 MB)

    // real pipeline — byte-identical to Round 4
    k_dot  <<<NN / 16, 256, 0, stream>>>(x, W, hraw);
    k_graph<<<BB, 1024, 0, stream>>>(hraw, b, src, dst,
                                     operm, tsvg, emask, nnn);
    k_feat <<<(BB * KK) / 8, 256, 0, stream>>>(x, operm, tsvg, feat);

    // shadow probes (results discarded; identical work, ws destinations)
    k_dot <<<NN / 16, 256, 0, stream>>>(x, W, sh_hraw);
    k_dot <<<NN / 16, 256, 0, stream>>>(x, W, sh_hraw);
    k_feat<<<(BB * KK) / 8, 256, 0, stream>>>(x, operm, tsvg, sh_feat);
    k_feat<<<(BB * KK) / 8, 256, 0, stream>>>(x, operm, tsvg, sh_feat);
    k_feat<<<(BB * KK) / 8, 256, 0, stream>>>(x, operm, tsvg, sh_feat);
    k_feat<<<(BB * KK) / 8, 256, 0, stream>>>(x, operm, tsvg, sh_feat);
}

// Round 7
// 260.383 us; speedup vs baseline: 1.4517x; 1.4517x over previous
//
#include <hip/hip_runtime.h>
#include <math.h>

// Static problem shape (from reference setup_inputs)
#define BB    256                // graphs
#define NPER  512                // nodes per graph
#define DD    256                // feature dim
#define KK    256                // kept nodes per graph
#define EPG   (NPER * 16)        // 8192 edges per graph
#define NN    (BB * NPER)
#define EE    (BB * EPG)

// native clang vector type — required by __builtin_nontemporal_store
typedef float vf4 __attribute__((ext_vector_type(4)));

// ---------------- k_dot: hraw[v] = dot(x[v], W) ----------------
// Persistent blocks: 2048 blocks x 256 thr (8/CU), 64 rows/block, 4 iters of
// wave-per-4-rows with 2-deep load pipeline (next iter's 4 float4 in flight
// during current reduction). No block churn; cold-stream at HBM BW.
__global__ __launch_bounds__(256) void k_dot(const float* __restrict__ x,
                                             const float* __restrict__ W,
                                             float* __restrict__ hraw) {
    const int wave = threadIdx.x >> 6;
    const int lane = threadIdx.x & 63;
    const float4 wv = ((const float4*)W)[lane];
    const int rb = blockIdx.x * 64 + wave * 4;          // this wave's iter-0 rows
    const float4* p = (const float4*)(x + ((size_t)rb << 8));

    float4 a0 = p[lane];
    float4 a1 = p[64 + lane];
    float4 a2 = p[128 + lane];
    float4 a3 = p[192 + lane];
    #pragma unroll
    for (int it = 0; it < 4; ++it) {
        float4 b0, b1, b2, b3;
        if (it < 3) {                                   // prefetch next 16-row group
            const float4* q = p + (size_t)(it + 1) * 1024;
            b0 = q[lane];
            b1 = q[64 + lane];
            b2 = q[128 + lane];
            b3 = q[192 + lane];
        }
        float d0 = a0.x * wv.x + a0.y * wv.y + a0.z * wv.z + a0.w * wv.w;
        float d1 = a1.x * wv.x + a1.y * wv.y + a1.z * wv.z + a1.w * wv.w;
        float d2 = a2.x * wv.x + a2.y * wv.y + a2.z * wv.z + a2.w * wv.w;
        float d3 = a3.x * wv.x + a3.y * wv.y + a3.z * wv.z + a3.w * wv.w;
        #pragma unroll
        for (int off = 32; off > 0; off >>= 1) {
            d0 += __shfl_down(d0, off, 64);
            d1 += __shfl_down(d1, off, 64);
            d2 += __shfl_down(d2, off, 64);
            d3 += __shfl_down(d3, off, 64);
        }
        if (lane == 0) {
            const int r = rb + it * 16;
            hraw[r]     = d0;
            hraw[r + 1] = d1;
            hraw[r + 2] = d2;
            hraw[r + 3] = d3;
        }
        a0 = b0; a1 = b1; a2 = b2; a3 = b3;
    }
}

// ---------------- k_graph: per-graph small-data pipeline, 1024 threads ------
__global__ __launch_bounds__(1024) void k_graph(
        const float* __restrict__ hraw, const float* __restrict__ b,
        const int* __restrict__ src, const int* __restrict__ dst,
        float* __restrict__ out_perm, float* __restrict__ tsvg,
        float* __restrict__ emask, float* __restrict__ nnn) {
    __shared__ unsigned int es2[EPG / 2];       // 16 KB packed src id pairs
    __shared__ unsigned int ed2[EPG / 2];       // 16 KB packed dst id pairs
    __shared__ int   degs[NPER];
    __shared__ int   degd[NPER];
    __shared__ float hl[NPER];
    __shared__ float aggl[NPER];
    __shared__ float scl[NPER];
    __shared__ unsigned long long keys[NPER];   // LDS stages of the sort
    __shared__ float keepf[NPER];               // 1.0 if kept else 0.0

    const int g = blockIdx.x;
    const int t = threadIdx.x;                  // 0..1023
    const int nbase = g << 9;

    // issue all global loads up front (edges + this thread's hraw)
    const int4* s4 = (const int4*)(src + (size_t)g * EPG);
    const int4* d4 = (const int4*)(dst + (size_t)g * EPG);
    int4 sva = s4[t], dva = d4[t];
    int4 svb = s4[t + 1024], dvb = d4[t + 1024];
    float hv = (t < NPER) ? hraw[nbase + t] : 0.0f;

    if (t < NPER) { degs[t] = 0; degd[t] = 0; aggl[t] = 0.0f; keepf[t] = 0.0f; }
    __syncthreads();

    // ---- pack edges to LDS + degree histograms ----
    {
        unsigned int a0 = (unsigned int)(sva.x - nbase), a1 = (unsigned int)(sva.y - nbase);
        unsigned int a2 = (unsigned int)(sva.z - nbase), a3 = (unsigned int)(sva.w - nbase);
        es2[t * 2]     = a0 | (a1 << 16);
        es2[t * 2 + 1] = a2 | (a3 << 16);
        atomicAdd(&degs[a0], 1); atomicAdd(&degs[a1], 1);
        atomicAdd(&degs[a2], 1); atomicAdd(&degs[a3], 1);
        unsigned int c0 = (unsigned int)(dva.x - nbase), c1 = (unsigned int)(dva.y - nbase);
        unsigned int c2 = (unsigned int)(dva.z - nbase), c3 = (unsigned int)(dva.w - nbase);
        ed2[t * 2]     = c0 | (c1 << 16);
        ed2[t * 2 + 1] = c2 | (c3 << 16);
        atomicAdd(&degd[c0], 1); atomicAdd(&degd[c1], 1);
        atomicAdd(&degd[c2], 1); atomicAdd(&degd[c3], 1);
    }
    {
        int i = t + 1024;
        unsigned int a0 = (unsigned int)(svb.x - nbase), a1 = (unsigned int)(svb.y - nbase);
        unsigned int a2 = (unsigned int)(svb.z - nbase), a3 = (unsigned int)(svb.w - nbase);
        es2[i * 2]     = a0 | (a1 << 16);
        es2[i * 2 + 1] = a2 | (a3 << 16);
        atomicAdd(&degs[a0], 1); atomicAdd(&degs[a1], 1);
        atomicAdd(&degs[a2], 1); atomicAdd(&degs[a3], 1);
        unsigned int c0 = (unsigned int)(dvb.x - nbase), c1 = (unsigned int)(dvb.y - nbase);
        unsigned int c2 = (unsigned int)(dvb.z - nbase), c3 = (unsigned int)(dvb.w - nbase);
        ed2[i * 2]     = c0 | (c1 << 16);
        ed2[i * 2 + 1] = c2 | (c3 << 16);
        atomicAdd(&degd[c0], 1); atomicAdd(&degd[c1], 1);
        atomicAdd(&degd[c2], 1); atomicAdd(&degd[c3], 1);
    }
    __syncthreads();

    // ---- h = hraw * rsqrt(max(deg_out,1)) ----
    if (t < NPER) hl[t] = hv * rsqrtf(fmaxf((float)degs[t], 1.0f));
    __syncthreads();

    // ---- agg[dst] += h[src]  (4 packed pairs per thread) ----
    #pragma unroll
    for (int i = t; i < EPG / 2; i += 1024) {
        unsigned int sp = es2[i], dp = ed2[i];
        atomicAdd(&aggl[dp & 0xFFFFu], hl[sp & 0xFFFFu]);
        atomicAdd(&aggl[dp >> 16],     hl[sp >> 16]);
    }
    __syncthreads();

    // ---- score + sort key (monotone float->uint; idx asc on ties) ----
    unsigned long long key = 0;
    if (t < NPER) {
        float sc = aggl[t] * rsqrtf(fmaxf((float)degd[t], 1.0f)) + b[0];
        scl[t] = sc;
        unsigned int u = __float_as_uint(sc);
        u = (u & 0x80000000u) ? ~u : (u | 0x80000000u);
        key = ((unsigned long long)u << 32) |
              (unsigned long long)(0xFFFFFFFFu - (unsigned)t);
    }
    __syncthreads();

    // ---- hybrid bitonic sort, 512 keys, descending, stable ----
    for (int kk = 2; kk <= NPER; kk <<= 1) {
        for (int j = kk >> 1; j > 0; j >>= 1) {
            if (j >= 64) {
                __syncthreads();                    // WAR: prior reads done
                if (t < NPER) keys[t] = key;
                __syncthreads();
                if (t < NPER) {
                    unsigned long long c = keys[t ^ j];
                    bool lower = ((t & j) == 0);
                    bool up    = ((t & kk) == 0);
                    bool takeMax = (up == lower);
                    key = takeMax ? (key >= c ? key : c)
                                  : (key >= c ? c : key);
                }
            } else {
                if (t < NPER) {
                    unsigned long long c = __shfl_xor(key, j, 64);
                    bool lower = ((t & j) == 0);
                    bool up    = ((t & kk) == 0);
                    bool takeMax = (up == lower);
                    key = takeMax ? (key >= c ? key : c)
                                  : (key >= c ? c : key);
                }
            }
        }
    }

    // ---- top-256: perm, keep flags, tanh(score) to global ----
    if (t < KK) {
        int idx = (int)(0xFFFFFFFFu - (unsigned int)(key & 0xFFFFFFFFull));
        out_perm[(g << 8) + t] = (float)(nbase + idx);
        tsvg[(g << 8) + t] = tanhf(scl[idx]);
        keepf[idx] = 1.0f;
    }
    __syncthreads();

    // ---- edge mask (packed LDS reads, non-temporal float4 stores) ----
    vf4* em4 = (vf4*)(emask + ((size_t)g << 13));
    #pragma unroll
    for (int i = t; i < EPG / 4; i += 1024) {
        unsigned int sp0 = es2[i * 2], sp1 = es2[i * 2 + 1];
        unsigned int dp0 = ed2[i * 2], dp1 = ed2[i * 2 + 1];
        vf4 m;
        m.x = keepf[sp0 & 0xFFFFu] * keepf[dp0 & 0xFFFFu];
        m.y = keepf[sp0 >> 16]     * keepf[dp0 >> 16];
        m.z = keepf[sp1 & 0xFFFFu] * keepf[dp1 & 0xFFFFu];
        m.w = keepf[sp1 >> 16]     * keepf[dp1 >> 16];
        __builtin_nontemporal_store(m, &em4[i]);
    }
    if (g == 0 && t < BB) nnn[t] = (float)KK;
}

// ---------------- k_feat: feat[r] = x[perm[r]] * tsv[r] ---------------------
// Persistent blocks: 2048 blocks x 256 thr, 32 rows/block, wave-per-2-rows x 4
// iters with 2-deep load pipeline. perm/tsv staged once per block.
__global__ __launch_bounds__(256) void k_feat(
        const float* __restrict__ x,
        const float* __restrict__ operm, const float* __restrict__ tsvg,
        float* __restrict__ feat) {
    __shared__ int   rsel[32];
    __shared__ float rts[32];
    const int out_base = blockIdx.x << 5;       // 32 output rows per block
    const int t = threadIdx.x;
    const int wave = t >> 6;
    const int lane = t & 63;
    if (t < 32) {
        const int gr = out_base + t;
        rsel[t] = (int)operm[gr];               // GLOBAL node id (exact in f32)
        rts[t]  = tsvg[gr];
    }
    __syncthreads();

    int j = wave << 3;                          // wave's first of 8 local rows
    float4 v0 = ((const float4*)(x + ((size_t)rsel[j]     << 8)))[lane];
    float4 v1 = ((const float4*)(x + ((size_t)rsel[j + 1] << 8)))[lane];
    #pragma unroll
    for (int it = 0; it < 4; ++it) {
        float4 n0, n1;
        if (it < 3) {                           // prefetch next 2 rows
            n0 = ((const float4*)(x + ((size_t)rsel[j + 2] << 8)))[lane];
            n1 = ((const float4*)(x + ((size_t)rsel[j + 3] << 8)))[lane];
        }
        const float s0 = rts[j], s1 = rts[j + 1];
        vf4 o0 = { v0.x * s0, v0.y * s0, v0.z * s0, v0.w * s0 };
        vf4 o1 = { v1.x * s1, v1.y * s1, v1.z * s1, v1.w * s1 };
        __builtin_nontemporal_store(
            o0, (vf4*)(feat + ((size_t)(out_base + j)     << 8)) + lane);
        __builtin_nontemporal_store(
            o1, (vf4*)(feat + ((size_t)(out_base + j + 1) << 8)) + lane);
        v0 = n0; v1 = n1; j += 2;
    }
}

extern "C" void kernel_launch(void* const* d_in, const int* in_sizes, int n_in,
                              void* d_out, int out_size, void* d_ws, size_t ws_size,
                              hipStream_t stream) {
    const float* x   = (const float*)d_in[0];
    const float* W   = (const float*)d_in[1];
    const float* b   = (const float*)d_in[2];
    const int*   src = (const int*)d_in[3];
    const int*   dst = (const int*)d_in[4];
    // d_in[5] = num_nodes (uniform 512, unused)

    float* out   = (float*)d_out;
    float* feat  = out;                                   // [B*k, D]
    float* operm = feat + (size_t)BB * KK * DD;           // [B*k]
    float* emask = operm + (size_t)BB * KK;               // [E]
    float* nnn   = emask + (size_t)EE;                    // [B]

    float* hraw = (float*)d_ws;                           // [N]
    float* tsvg = hraw + NN;                              // [B*k]

    k_dot  <<<NN / 64, 256, 0, stream>>>(x, W, hraw);       // 2048 blocks
    k_graph<<<BB, 1024, 0, stream>>>(hraw, b, src, dst,
                                     operm, tsvg, emask, nnn);
    k_feat <<<(BB * KK) / 32, 256, 0, stream>>>(x, operm, tsvg, feat); // 2048
}

// Round 8
// 254.362 us; speedup vs baseline: 1.4861x; 1.0237x over previous
//
#include <hip/hip_runtime.h>
#include <math.h>

// Static problem shape (from reference setup_inputs)
#define BB    256                // graphs
#define NPER  512                // nodes per graph
#define DD    256                // feature dim
#define KK    256                // kept nodes per graph
#define EPG   (NPER * 16)        // 8192 edges per graph
#define NN    (BB * NPER)
#define EE    (BB * EPG)

// ---------------- k_dot: hraw[v] = dot(x[v], W) ----------------
// wave per 4 rows (ILP), 256-thread blocks -> 16 rows/block, 8192 blocks
__global__ __launch_bounds__(256) void k_dot(const float* __restrict__ x,
                                             const float* __restrict__ W,
                                             float* __restrict__ hraw) {
    const int wave = threadIdx.x >> 6;
    const int lane = threadIdx.x & 63;
    const int r0   = blockIdx.x * 16 + wave * 4;
    const float4 wv = ((const float4*)W)[lane];
    const float4* p = (const float4*)(x + ((size_t)r0 << 8));
    float4 a0 = p[lane];
    float4 a1 = p[64 + lane];
    float4 a2 = p[128 + lane];
    float4 a3 = p[192 + lane];
    float d0 = a0.x * wv.x + a0.y * wv.y + a0.z * wv.z + a0.w * wv.w;
    float d1 = a1.x * wv.x + a1.y * wv.y + a1.z * wv.z + a1.w * wv.w;
    float d2 = a2.x * wv.x + a2.y * wv.y + a2.z * wv.z + a2.w * wv.w;
    float d3 = a3.x * wv.x + a3.y * wv.y + a3.z * wv.z + a3.w * wv.w;
    #pragma unroll
    for (int off = 32; off > 0; off >>= 1) {
        d0 += __shfl_down(d0, off, 64);
        d1 += __shfl_down(d1, off, 64);
        d2 += __shfl_down(d2, off, 64);
        d3 += __shfl_down(d3, off, 64);
    }
    if (lane == 0) {
        hraw[r0]     = d0;
        hraw[r0 + 1] = d1;
        hraw[r0 + 2] = d2;
        hraw[r0 + 3] = d3;
    }
}

// ---------------- k_graph: per-graph pipeline, 1024 threads ----------------
// edges+degrees -> scale h -> LDS agg -> score -> hybrid bitonic top-256
// -> feat gather+scale -> edge mask   (one block per graph, no global syncs)
__global__ __launch_bounds__(1024) void k_graph(
        const float* __restrict__ x,
        const float* __restrict__ hraw, const float* __restrict__ b,
        const int* __restrict__ src, const int* __restrict__ dst,
        float* __restrict__ feat, float* __restrict__ out_perm,
        float* __restrict__ emask, float* __restrict__ nnn) {
    __shared__ unsigned int es2[EPG / 2];       // 16 KB packed src id pairs
    __shared__ unsigned int ed2[EPG / 2];       // 16 KB packed dst id pairs
    __shared__ int   degs[NPER];
    __shared__ int   degd[NPER];
    __shared__ float hl[NPER];
    __shared__ float aggl[NPER];
    __shared__ float scl[NPER];
    __shared__ unsigned long long keys[NPER];   // LDS stages of the sort
    __shared__ float keepf[NPER];               // 1.0 if kept else 0.0
    __shared__ int   sel[KK];                   // rank -> local node id
    __shared__ float tsv[KK];                   // rank -> tanh(score)

    const int g = blockIdx.x;
    const int t = threadIdx.x;                  // 0..1023
    const int wave = t >> 6;
    const int lane = t & 63;
    const int nbase = g << 9;

    // pre-load hraw for this thread's node (hidden behind edge phase)
    float hv = (t < NPER) ? hraw[nbase + t] : 0.0f;

    if (t < NPER) { degs[t] = 0; degd[t] = 0; aggl[t] = 0.0f; keepf[t] = 0.0f; }
    __syncthreads();

    // ---- edge load (all 4 int4 loads issued up front) + degree histograms ----
    const int4* s4 = (const int4*)(src + (size_t)g * EPG);
    const int4* d4 = (const int4*)(dst + (size_t)g * EPG);
    int4 sva = s4[t], dva = d4[t];
    int4 svb = s4[t + 1024], dvb = d4[t + 1024];
    {
        unsigned int a0 = (unsigned int)(sva.x - nbase), a1 = (unsigned int)(sva.y - nbase);
        unsigned int a2 = (unsigned int)(sva.z - nbase), a3 = (unsigned int)(sva.w - nbase);
        es2[t * 2]     = a0 | (a1 << 16);
        es2[t * 2 + 1] = a2 | (a3 << 16);
        atomicAdd(&degs[a0], 1); atomicAdd(&degs[a1], 1);
        atomicAdd(&degs[a2], 1); atomicAdd(&degs[a3], 1);
        unsigned int c0 = (unsigned int)(dva.x - nbase), c1 = (unsigned int)(dva.y - nbase);
        unsigned int c2 = (unsigned int)(dva.z - nbase), c3 = (unsigned int)(dva.w - nbase);
        ed2[t * 2]     = c0 | (c1 << 16);
        ed2[t * 2 + 1] = c2 | (c3 << 16);
        atomicAdd(&degd[c0], 1); atomicAdd(&degd[c1], 1);
        atomicAdd(&degd[c2], 1); atomicAdd(&degd[c3], 1);
    }
    {
        int i = t + 1024;
        unsigned int a0 = (unsigned int)(svb.x - nbase), a1 = (unsigned int)(svb.y - nbase);
        unsigned int a2 = (unsigned int)(svb.z - nbase), a3 = (unsigned int)(svb.w - nbase);
        es2[i * 2]     = a0 | (a1 << 16);
        es2[i * 2 + 1] = a2 | (a3 << 16);
        atomicAdd(&degs[a0], 1); atomicAdd(&degs[a1], 1);
        atomicAdd(&degs[a2], 1); atomicAdd(&degs[a3], 1);
        unsigned int c0 = (unsigned int)(dvb.x - nbase), c1 = (unsigned int)(dvb.y - nbase);
        unsigned int c2 = (unsigned int)(dvb.z - nbase), c3 = (unsigned int)(dvb.w - nbase);
        ed2[i * 2]     = c0 | (c1 << 16);
        ed2[i * 2 + 1] = c2 | (c3 << 16);
        atomicAdd(&degd[c0], 1); atomicAdd(&degd[c1], 1);
        atomicAdd(&degd[c2], 1); atomicAdd(&degd[c3], 1);
    }
    __syncthreads();

    // ---- h = hraw * rsqrt(max(deg_out,1)) ----
    if (t < NPER) hl[t] = hv * rsqrtf(fmaxf((float)degs[t], 1.0f));
    __syncthreads();

    // ---- agg[dst] += h[src]  (4 packed pairs per thread) ----
    #pragma unroll
    for (int i = t; i < EPG / 2; i += 1024) {
        unsigned int sp = es2[i], dp = ed2[i];
        atomicAdd(&aggl[dp & 0xFFFFu], hl[sp & 0xFFFFu]);
        atomicAdd(&aggl[dp >> 16],     hl[sp >> 16]);
    }
    __syncthreads();

    // ---- score + sort key (monotone float->uint; idx asc on ties) ----
    unsigned long long key = 0;
    if (t < NPER) {
        float sc = aggl[t] * rsqrtf(fmaxf((float)degd[t], 1.0f)) + b[0];
        scl[t] = sc;
        unsigned int u = __float_as_uint(sc);
        u = (u & 0x80000000u) ? ~u : (u | 0x80000000u);
        key = ((unsigned long long)u << 32) |
              (unsigned long long)(0xFFFFFFFFu - (unsigned)t);
    }
    __syncthreads();

    // ---- hybrid bitonic sort, 512 keys, descending, stable ----
    // j < 64  -> wave-local shfl_xor stages (no barriers)
    // j >= 64 -> LDS exchange (6 stages total)
    for (int kk = 2; kk <= NPER; kk <<= 1) {
        for (int j = kk >> 1; j > 0; j >>= 1) {
            if (j >= 64) {
                __syncthreads();                    // WAR: prior reads done
                if (t < NPER) keys[t] = key;
                __syncthreads();
                if (t < NPER) {
                    unsigned long long c = keys[t ^ j];
                    bool lower = ((t & j) == 0);
                    bool up    = ((t & kk) == 0);
                    bool takeMax = (up == lower);
                    key = takeMax ? (key >= c ? key : c)
                                  : (key >= c ? c : key);
                }
            } else {
                if (t < NPER) {
                    unsigned long long c = __shfl_xor(key, j, 64);
                    bool lower = ((t & j) == 0);
                    bool up    = ((t & kk) == 0);
                    bool takeMax = (up == lower);
                    key = takeMax ? (key >= c ? key : c)
                                  : (key >= c ? c : key);
                }
            }
        }
    }

    // ---- top-256: perm, keep flags, sel, tanh(score) ----
    if (t < KK) {
        int idx = (int)(0xFFFFFFFFu - (unsigned int)(key & 0xFFFFFFFFull));
        out_perm[(g << 8) + t] = (float)(nbase + idx);
        sel[t] = idx;
        tsv[t] = tanhf(scl[idx]);
        keepf[idx] = 1.0f;
    }
    __syncthreads();

    // ---- feat = x[sel] * tanh(score)  (wave per row, 16 rows/wave) ----
    #pragma unroll
    for (int it = 0; it < 16; it += 2) {
        const int j0 = wave * 16 + it, j1 = j0 + 1;
        const int l0 = sel[j0], l1 = sel[j1];
        const float s0 = tsv[j0], s1 = tsv[j1];
        const float4* q0 = (const float4*)(x + ((size_t)(nbase + l0) << 8));
        const float4* q1 = (const float4*)(x + ((size_t)(nbase + l1) << 8));
        float4 v0 = q0[lane], v1 = q1[lane];
        float4 o0 = make_float4(v0.x * s0, v0.y * s0, v0.z * s0, v0.w * s0);
        float4 o1 = make_float4(v1.x * s1, v1.y * s1, v1.z * s1, v1.w * s1);
        ((float4*)(feat + ((size_t)((g << 8) + j0) << 8)))[lane] = o0;
        ((float4*)(feat + ((size_t)((g << 8) + j1) << 8)))[lane] = o1;
    }

    // ---- edge mask (packed LDS reads, float4 stores) ----
    float4* em4 = (float4*)(emask + ((size_t)g << 13));
    #pragma unroll
    for (int i = t; i < EPG / 4; i += 1024) {
        unsigned int sp0 = es2[i * 2], sp1 = es2[i * 2 + 1];
        unsigned int dp0 = ed2[i * 2], dp1 = ed2[i * 2 + 1];
        float4 m;
        m.x = keepf[sp0 & 0xFFFFu] * keepf[dp0 & 0xFFFFu];
        m.y = keepf[sp0 >> 16]     * keepf[dp0 >> 16];
        m.z = keepf[sp1 & 0xFFFFu] * keepf[dp1 & 0xFFFFu];
        m.w = keepf[sp1 >> 16]     * keepf[dp1 >> 16];
        em4[i] = m;
    }
    if (g == 0 && t < BB) nnn[t] = (float)KK;
}

extern "C" void kernel_launch(void* const* d_in, const int* in_sizes, int n_in,
                              void* d_out, int out_size, void* d_ws, size_t ws_size,
                              hipStream_t stream) {
    const float* x   = (const float*)d_in[0];
    const float* W   = (const float*)d_in[1];
    const float* b   = (const float*)d_in[2];
    const int*   src = (const int*)d_in[3];
    const int*   dst = (const int*)d_in[4];
    // d_in[5] = num_nodes (uniform 512, unused)

    float* out   = (float*)d_out;
    float* feat  = out;                                   // [B*k, D]
    float* operm = feat + (size_t)BB * KK * DD;           // [B*k]
    float* emask = operm + (size_t)BB * KK;               // [E]
    float* nnn   = emask + (size_t)EE;                    // [B]

    float* hraw = (float*)d_ws;                           // [N] scratch

    k_dot  <<<NN / 16, 256, 0, stream>>>(x, W, hraw);
    k_graph<<<BB, 1024, 0, stream>>>(x, hraw, b, src, dst,
                                     feat, operm, emask, nnn);
}